// Round 1
// baseline (1242.825 us; speedup 1.0000x reference)
//
#include <hip/hip_runtime.h>
#include <cstdint>

constexpr int Sd = 2048;   // sequence length
constexpr int Dd = 1024;   // embed dim
constexpr int Hd = 16;     // heads
constexpr int Dh = 64;     // head dim
constexpr int Bd = 2;      // batch

// ---------------------------------------------------------------------------
// 64x64-tile fp32 GEMM, 256 threads, 4x4 per thread.
// A [M,K] row-major, B [K,N] row-major, C [M,N] (PERMUTE=false)
// PERMUTE=true: C written as [B,H,S,Dh] (head-split layout) for Q/K/V.
// ---------------------------------------------------------------------------
template <bool PERMUTE>
__global__ __launch_bounds__(256) void sgemm64(const float* __restrict__ A,
                                               const float* __restrict__ B,
                                               float* __restrict__ C,
                                               int M, int N, int K) {
  __shared__ float As[16][68];  // [k][m], pad->2-way bank aliasing (free)
  __shared__ float Bs[16][64];  // [k][n]
  const int t  = threadIdx.x;
  const int tx = t & 15;
  const int ty = t >> 4;
  const int bm = blockIdx.y * 64;
  const int bn = blockIdx.x * 64;

  float acc[4][4] = {};

  for (int k0 = 0; k0 < K; k0 += 16) {
#pragma unroll
    for (int i = 0; i < 4; ++i) {
      int idx = t + 256 * i;
      int am = idx >> 4, ak = idx & 15;
      As[ak][am] = A[(size_t)(bm + am) * K + k0 + ak];
      int bk = idx >> 6, bnn = idx & 63;
      Bs[bk][bnn] = B[(size_t)(k0 + bk) * N + bn + bnn];
    }
    __syncthreads();
#pragma unroll
    for (int kk = 0; kk < 16; ++kk) {
      const float4 av = *(const float4*)&As[kk][ty * 4];
      const float4 bv = *(const float4*)&Bs[kk][tx * 4];
      const float a[4] = {av.x, av.y, av.z, av.w};
      const float b[4] = {bv.x, bv.y, bv.z, bv.w};
#pragma unroll
      for (int i = 0; i < 4; ++i)
#pragma unroll
        for (int j = 0; j < 4; ++j)
          acc[i][j] = fmaf(a[i], b[j], acc[i][j]);
    }
    __syncthreads();
  }

#pragma unroll
  for (int i = 0; i < 4; ++i) {
    float4 o = make_float4(acc[i][0], acc[i][1], acc[i][2], acc[i][3]);
    int m = bm + ty * 4 + i;
    int n = bn + tx * 4;
    if (PERMUTE) {
      int b = m >> 11, s = m & (Sd - 1);   // S = 2048
      int h = n >> 6,  d = n & (Dh - 1);   // Dh = 64
      *(float4*)&C[(((size_t)(b * Hd + h) * Sd + s) * Dh) + d] = o;
    } else {
      *(float4*)&C[(size_t)m * N + n] = o;
    }
  }
}

// ---------------------------------------------------------------------------
// Flash-style causal attention, fp32.
// Q,K,V: [B,H,S,Dh].  Output written as [B,S,D] (heads re-interleaved).
// One block = one (b,h) x 64 query rows. 256 threads.
// thread t: qi in {ty*4+i}, score cols kj in {tx+16j}, O cols d in {tx*4+jd}.
// Row-group = 16 contiguous lanes (same ty) -> shfl_xor reductions in-wave.
// ---------------------------------------------------------------------------
__global__ __launch_bounds__(256) void attn64(const float* __restrict__ Q,
                                              const float* __restrict__ K,
                                              const float* __restrict__ V,
                                              float* __restrict__ O) {
  __shared__ float Qs[64][68];
  __shared__ float Ks[64][68];
  __shared__ float Vs[64][68];
  __shared__ float Ps[64][68];

  const int t  = threadIdx.x;
  const int tx = t & 15;
  const int ty = t >> 4;
  const int qt = blockIdx.x;          // query tile
  const int bh = blockIdx.y;          // b*H + h
  const int b  = bh >> 4;
  const int h  = bh & 15;
  const int q0 = qt * 64;

  // ---- load Q tile (contiguous 16 KB), apply 1/sqrt(Dh) scale ----
  const float4* Qbase = (const float4*)(Q + ((size_t)bh * Sd + q0) * Dh);
#pragma unroll
  for (int i = 0; i < 4; ++i) {
    int idx = t + 256 * i;            // float4 index 0..1023
    int r = idx >> 4, c = idx & 15;
    float4 v = Qbase[idx];
    v.x *= 0.125f; v.y *= 0.125f; v.z *= 0.125f; v.w *= 0.125f;
    *(float4*)&Qs[r][c * 4] = v;
  }

  float Oa[4][4] = {};
  float mrow[4] = {-1e30f, -1e30f, -1e30f, -1e30f};
  float lrow[4] = {};

  for (int kt = 0; kt <= qt; ++kt) {
    __syncthreads();                  // previous PV done before overwriting
    const float4* Kbase = (const float4*)(K + ((size_t)bh * Sd + kt * 64) * Dh);
    const float4* Vbase = (const float4*)(V + ((size_t)bh * Sd + kt * 64) * Dh);
#pragma unroll
    for (int i = 0; i < 4; ++i) {
      int idx = t + 256 * i;
      int r = idx >> 4, c = idx & 15;
      *(float4*)&Ks[r][c * 4] = Kbase[idx];
      *(float4*)&Vs[r][c * 4] = Vbase[idx];
    }
    __syncthreads();

    // ---- scores: sc[i][j] = Qrow(ty*4+i) . Krow(tx+16j) ----
    float sc[4][4] = {};
#pragma unroll
    for (int d = 0; d < 64; d += 4) {
      float4 qv[4], kv[4];
#pragma unroll
      for (int i = 0; i < 4; ++i) qv[i] = *(const float4*)&Qs[ty * 4 + i][d];
#pragma unroll
      for (int j = 0; j < 4; ++j) kv[j] = *(const float4*)&Ks[tx + 16 * j][d];
#pragma unroll
      for (int i = 0; i < 4; ++i)
#pragma unroll
        for (int j = 0; j < 4; ++j)
          sc[i][j] += qv[i].x * kv[j].x + qv[i].y * kv[j].y +
                      qv[i].z * kv[j].z + qv[i].w * kv[j].w;
    }

    if (kt == qt) {                   // causal mask on the diagonal tile
#pragma unroll
      for (int i = 0; i < 4; ++i)
#pragma unroll
        for (int j = 0; j < 4; ++j)
          if (tx + 16 * j > ty * 4 + i) sc[i][j] = -1e30f;
    }

    // ---- online softmax (per row, reduce over 16 lanes) ----
#pragma unroll
    for (int i = 0; i < 4; ++i) {
      float rm = fmaxf(fmaxf(sc[i][0], sc[i][1]), fmaxf(sc[i][2], sc[i][3]));
#pragma unroll
      for (int off = 1; off < 16; off <<= 1)
        rm = fmaxf(rm, __shfl_xor(rm, off));
      float mnew = fmaxf(mrow[i], rm);
      float fac  = __expf(mrow[i] - mnew);
      mrow[i] = mnew;
      float rs = 0.f;
#pragma unroll
      for (int j = 0; j < 4; ++j) {
        sc[i][j] = __expf(sc[i][j] - mnew);
        rs += sc[i][j];
      }
#pragma unroll
      for (int off = 1; off < 16; off <<= 1)
        rs += __shfl_xor(rs, off);
      lrow[i] = lrow[i] * fac + rs;
#pragma unroll
      for (int jd = 0; jd < 4; ++jd) Oa[i][jd] *= fac;
#pragma unroll
      for (int j = 0; j < 4; ++j) Ps[ty * 4 + i][tx + 16 * j] = sc[i][j];
    }
    __syncthreads();

    // ---- O += P @ V  (4x4 per thread, float4 LDS reads) ----
#pragma unroll
    for (int k4 = 0; k4 < 16; ++k4) {
      float4 pv[4], vv[4];
#pragma unroll
      for (int i = 0; i < 4; ++i) pv[i] = *(const float4*)&Ps[ty * 4 + i][k4 * 4];
#pragma unroll
      for (int kk = 0; kk < 4; ++kk) vv[kk] = *(const float4*)&Vs[k4 * 4 + kk][tx * 4];
#pragma unroll
      for (int i = 0; i < 4; ++i) {
        const float p[4] = {pv[i].x, pv[i].y, pv[i].z, pv[i].w};
#pragma unroll
        for (int kk = 0; kk < 4; ++kk) {
          Oa[i][0] = fmaf(p[kk], vv[kk].x, Oa[i][0]);
          Oa[i][1] = fmaf(p[kk], vv[kk].y, Oa[i][1]);
          Oa[i][2] = fmaf(p[kk], vv[kk].z, Oa[i][2]);
          Oa[i][3] = fmaf(p[kk], vv[kk].w, Oa[i][3]);
        }
      }
    }
  }

  // ---- epilogue: normalize, store to [B,S,D] with heads interleaved ----
#pragma unroll
  for (int i = 0; i < 4; ++i) {
    float inv = 1.0f / lrow[i];
    int qi = ty * 4 + i;
    float4 o = make_float4(Oa[i][0] * inv, Oa[i][1] * inv,
                           Oa[i][2] * inv, Oa[i][3] * inv);
    *(float4*)&O[((size_t)(b * Sd + q0 + qi) * Dd) + h * Dh + tx * 4] = o;
  }
}

// ---------------------------------------------------------------------------
extern "C" void kernel_launch(void* const* d_in, const int* in_sizes, int n_in,
                              void* d_out, int out_size, void* d_ws, size_t ws_size,
                              hipStream_t stream) {
  const float* x  = (const float*)d_in[0];
  const float* Wq = (const float*)d_in[1];
  const float* Wk = (const float*)d_in[2];
  const float* Wv = (const float*)d_in[3];
  const float* Wo = (const float*)d_in[4];
  float* out = (float*)d_out;

  const size_t tsz = (size_t)Bd * Sd * Dd;  // 4,194,304 elements (16 MB)
  float* Qb = (float*)d_ws;
  float* Kb = Qb + tsz;
  float* Vb = Kb + tsz;
  float* Ab = Vb + tsz;   // attention output, [B,S,D]

  const int M = Bd * Sd;  // 4096
  dim3 blk(256);
  dim3 grid_g(Dd / 64, M / 64);      // (16, 64)
  dim3 grid_a(Sd / 64, Bd * Hd);     // (32, 32)

  hipLaunchKernelGGL((sgemm64<true>),  grid_g, blk, 0, stream, x,  Wq, Qb, M, Dd, Dd);
  hipLaunchKernelGGL((sgemm64<true>),  grid_g, blk, 0, stream, x,  Wk, Kb, M, Dd, Dd);
  hipLaunchKernelGGL((sgemm64<true>),  grid_g, blk, 0, stream, x,  Wv, Vb, M, Dd, Dd);
  hipLaunchKernelGGL(attn64,           grid_a, blk, 0, stream, Qb, Kb, Vb, Ab);
  hipLaunchKernelGGL((sgemm64<false>), grid_g, blk, 0, stream, Ab, Wo, out, M, Dd, Dd);
}

// Round 2
// 298.917 us; speedup vs baseline: 4.1578x; 4.1578x over previous
//
#include <hip/hip_runtime.h>
#include <cstdint>

typedef __bf16 bf16;
typedef __bf16 bf16x4 __attribute__((ext_vector_type(4)));
typedef __bf16 bf16x8 __attribute__((ext_vector_type(8)));
typedef float f32x4 __attribute__((ext_vector_type(4)));

constexpr int Sd = 2048, Dd = 1024, Hd = 16, Dh = 64, Bd = 2;

__device__ __forceinline__ f32x4 mfma16(bf16x8 a, bf16x8 b, f32x4 c) {
  return __builtin_amdgcn_mfma_f32_16x16x32_bf16(a, b, c, 0, 0, 0);
}

// ---------------------------------------------------------------------------
// bf16 MFMA GEMM: C[M,N] = A[M,K] * B[K,N].
// A: fp32 (A_BF16=false, converted in staging) or bf16 (A_BF16=true).
// B: fp32 weights, staged transposed as bf16.
// PERMUTE: write bf16 to [B,H,S,Dh]; else fp32 row-major [M,N].
// Tile 128x64, BK=32, 256 threads = 4 waves (2x2), 8 MFMA / K-step / wave.
// ---------------------------------------------------------------------------
template <bool A_BF16, bool PERMUTE>
__global__ __launch_bounds__(256) void gemm_mfma(const void* __restrict__ Ap,
                                                 const float* __restrict__ Bp,
                                                 void* __restrict__ Cp,
                                                 int M, int N, int K) {
  constexpr int BM = 128, BN = 64, BK = 32, LK = 40;  // LK: padded k (80 B rows)
  __shared__ __align__(16) bf16 As[BM][LK];
  __shared__ __align__(16) bf16 Bt[BN][LK];

  const int t = threadIdx.x;
  const int lane = t & 63;
  const int w = t >> 6;
  const int wm = w >> 1, wn = w & 1;
  const int g = lane >> 4, c = lane & 15;
  const int bm = blockIdx.y * BM, bn = blockIdx.x * BN;

  f32x4 acc[4][2] = {};

  for (int k0 = 0; k0 < K; k0 += BK) {
    __syncthreads();
    // ---- stage A tile (128 x 32) ----
    if constexpr (A_BF16) {
      const bf16* A = (const bf16*)Ap;
#pragma unroll
      for (int p = 0; p < 2; ++p) {
        int idx = t + 256 * p;              // 512 chunks of 8 bf16
        int row = idx >> 2, cg = idx & 3;
        *(bf16x8*)&As[row][cg * 8] =
            *(const bf16x8*)&A[(size_t)(bm + row) * K + k0 + cg * 8];
      }
    } else {
      const float* A = (const float*)Ap;
#pragma unroll
      for (int p = 0; p < 4; ++p) {
        int idx = t + 256 * p;              // 1024 chunks of 4 fp32
        int row = idx >> 3, cg = idx & 7;
        const float4 v = *(const float4*)&A[(size_t)(bm + row) * K + k0 + cg * 4];
        bf16x4 o = {(bf16)v.x, (bf16)v.y, (bf16)v.z, (bf16)v.w};
        *(bf16x4*)&As[row][cg * 4] = o;
      }
    }
    // ---- stage B tile (32 x 64) transposed -> Bt[n][k] ----
#pragma unroll
    for (int p = 0; p < 2; ++p) {
      int idx = t + 256 * p;                // 512 chunks of 4 fp32
      int kk = idx >> 4, ng = (idx & 15) * 4;
      const float4 v = *(const float4*)&Bp[(size_t)(k0 + kk) * N + bn + ng];
      Bt[ng + 0][kk] = (bf16)v.x;
      Bt[ng + 1][kk] = (bf16)v.y;
      Bt[ng + 2][kk] = (bf16)v.z;
      Bt[ng + 3][kk] = (bf16)v.w;
    }
    __syncthreads();

    // ---- fragments + MFMA ----
    bf16x8 af[4], bfr[2];
#pragma unroll
    for (int mi = 0; mi < 4; ++mi)
      af[mi] = *(const bf16x8*)&As[wm * 64 + mi * 16 + c][g * 8];
#pragma unroll
    for (int ni = 0; ni < 2; ++ni)
      bfr[ni] = *(const bf16x8*)&Bt[wn * 32 + ni * 16 + c][g * 8];
#pragma unroll
    for (int mi = 0; mi < 4; ++mi)
#pragma unroll
      for (int ni = 0; ni < 2; ++ni)
        acc[mi][ni] = mfma16(af[mi], bfr[ni], acc[mi][ni]);
  }

  // ---- epilogue (C frag: row = 4g+r, col = c) ----
#pragma unroll
  for (int mi = 0; mi < 4; ++mi)
#pragma unroll
    for (int ni = 0; ni < 2; ++ni)
#pragma unroll
      for (int r = 0; r < 4; ++r) {
        const int m = bm + wm * 64 + mi * 16 + g * 4 + r;
        const int n = bn + wn * 32 + ni * 16 + c;
        const float v = acc[mi][ni][r];
        if constexpr (PERMUTE) {
          const int b = m >> 11, s = m & (Sd - 1);
          const int h = n >> 6, d = n & (Dh - 1);
          ((bf16*)Cp)[(((size_t)(b * Hd + h) * Sd + s) * Dh) + d] = (bf16)v;
        } else {
          ((float*)Cp)[(size_t)m * N + n] = v;
        }
      }
}

// ---------------------------------------------------------------------------
// Flash attention, bf16 MFMA. Q,K,V bf16 [B,H,S,Dh]; out bf16 [B,S,D].
// Block: 256 thr = 4 waves; 64 q-rows (16/wave); K-tile 64.
// Q frags in registers; K row-major LDS; V transposed in LDS; P via LDS.
// Scale 1/8 folded into exp2 argument.
// ---------------------------------------------------------------------------
__global__ __launch_bounds__(256) void attn_mfma(const bf16* __restrict__ Q,
                                                 const bf16* __restrict__ K,
                                                 const bf16* __restrict__ V,
                                                 bf16* __restrict__ O) {
  constexpr int LKD = 72;  // padded row (144 B): 16B-aligned, conflict-free
  __shared__ __align__(16) bf16 Ks[64][LKD];
  __shared__ __align__(16) bf16 Vt[64][LKD];       // [vd][kv]
  __shared__ __align__(16) bf16 Ps[4][16][LKD];    // per-wave P

  const int t = threadIdx.x;
  const int lane = t & 63, w = t >> 6;
  const int g = lane >> 4, c = lane & 15;
  const int qt = blockIdx.x, bh = blockIdx.y;
  const int q0 = qt * 64;
  const int b = bh >> 4, h = bh & 15;

  // Q fragments: rows q0+16w+c, k-halves (d 0..31 / 32..63)
  const bf16* Qrow = Q + ((size_t)bh * Sd + q0 + 16 * w + c) * Dh;
  bf16x8 qf[2];
  qf[0] = *(const bf16x8*)&Qrow[g * 8];
  qf[1] = *(const bf16x8*)&Qrow[32 + g * 8];

  f32x4 oacc[4] = {};
  float mrow[4] = {-1e30f, -1e30f, -1e30f, -1e30f};
  float lrow[4] = {0.f, 0.f, 0.f, 0.f};
  const float SC = 0.18033688011112042f;  // (1/8) * log2(e)

  for (int kt = 0; kt <= qt; ++kt) {
    __syncthreads();  // previous tile's MFMA reads done
    // ---- stage K tile (row-major) ----
    const bf16* Kg = K + ((size_t)bh * Sd + kt * 64) * Dh;
#pragma unroll
    for (int p = 0; p < 2; ++p) {
      int idx = t + 256 * p;
      int kv = idx >> 3, dg = idx & 7;
      *(bf16x8*)&Ks[kv][dg * 8] = *(const bf16x8*)&Kg[kv * 64 + dg * 8];
    }
    // ---- stage V tile transposed (kv-pair packed u32 writes) ----
    const bf16* Vg = V + ((size_t)bh * Sd + kt * 64) * Dh;
    {
      const int p2 = t & 31, dg = t >> 5;
      bf16x8 v0 = *(const bf16x8*)&Vg[(2 * p2) * 64 + dg * 8];
      bf16x8 v1 = *(const bf16x8*)&Vg[(2 * p2 + 1) * 64 + dg * 8];
      union { bf16 h2[2]; uint32_t u; } pk;
#pragma unroll
      for (int i = 0; i < 8; ++i) {
        pk.h2[0] = v0[i];
        pk.h2[1] = v1[i];
        *(uint32_t*)&Vt[dg * 8 + i][2 * p2] = pk.u;
      }
    }
    __syncthreads();

    // ---- S = Q K^T (raw, unscaled) ----
    f32x4 sc4[4];
#pragma unroll
    for (int ct = 0; ct < 4; ++ct) {
      f32x4 s = {};
      s = mfma16(qf[0], *(const bf16x8*)&Ks[ct * 16 + c][g * 8], s);
      s = mfma16(qf[1], *(const bf16x8*)&Ks[ct * 16 + c][32 + g * 8], s);
      sc4[ct] = s;
    }

    // ---- online softmax per row (rows 4g+r, cols 16ct+c) ----
#pragma unroll
    for (int r = 0; r < 4; ++r) {
      float s0 = sc4[0][r], s1 = sc4[1][r], s2 = sc4[2][r], s3 = sc4[3][r];
      if (kt == qt) {
        const int qg = q0 + 16 * w + 4 * g + r;
        if (kt * 64 + 0  + c > qg) s0 = -1e30f;
        if (kt * 64 + 16 + c > qg) s1 = -1e30f;
        if (kt * 64 + 32 + c > qg) s2 = -1e30f;
        if (kt * 64 + 48 + c > qg) s3 = -1e30f;
      }
      float mt = fmaxf(fmaxf(s0, s1), fmaxf(s2, s3));
#pragma unroll
      for (int off = 1; off < 16; off <<= 1)
        mt = fmaxf(mt, __shfl_xor(mt, off));
      const float mnew = fmaxf(mrow[r], mt);
      const float fac = exp2f((mrow[r] - mnew) * SC);
      mrow[r] = mnew;
      const float p0 = exp2f((s0 - mnew) * SC);
      const float p1 = exp2f((s1 - mnew) * SC);
      const float p2 = exp2f((s2 - mnew) * SC);
      const float p3 = exp2f((s3 - mnew) * SC);
      float ls = p0 + p1 + p2 + p3;
#pragma unroll
      for (int off = 1; off < 16; off <<= 1)
        ls += __shfl_xor(ls, off);
      lrow[r] = lrow[r] * fac + ls;
#pragma unroll
      for (int ct = 0; ct < 4; ++ct) oacc[ct][r] *= fac;
      Ps[w][4 * g + r][0  + c] = (bf16)p0;
      Ps[w][4 * g + r][16 + c] = (bf16)p1;
      Ps[w][4 * g + r][32 + c] = (bf16)p2;
      Ps[w][4 * g + r][48 + c] = (bf16)p3;
    }

    // ---- O += P V (A from Ps, B from Vt; per-wave, no barrier needed) ----
    bf16x8 pa[2];
    pa[0] = *(const bf16x8*)&Ps[w][c][g * 8];
    pa[1] = *(const bf16x8*)&Ps[w][c][32 + g * 8];
#pragma unroll
    for (int ct = 0; ct < 4; ++ct) {
      oacc[ct] = mfma16(pa[0], *(const bf16x8*)&Vt[ct * 16 + c][g * 8], oacc[ct]);
      oacc[ct] = mfma16(pa[1], *(const bf16x8*)&Vt[ct * 16 + c][32 + g * 8], oacc[ct]);
    }
  }

  // ---- epilogue: normalize, write bf16 [B,S,D] ----
  float inv[4];
#pragma unroll
  for (int r = 0; r < 4; ++r) inv[r] = 1.0f / lrow[r];
#pragma unroll
  for (int ct = 0; ct < 4; ++ct)
#pragma unroll
    for (int r = 0; r < 4; ++r) {
      const int s = q0 + 16 * w + 4 * g + r;
      const int d = h * 64 + 16 * ct + c;
      O[((size_t)b * Sd + s) * Dd + d] = (bf16)(oacc[ct][r] * inv[r]);
    }
}

// ---------------------------------------------------------------------------
extern "C" void kernel_launch(void* const* d_in, const int* in_sizes, int n_in,
                              void* d_out, int out_size, void* d_ws, size_t ws_size,
                              hipStream_t stream) {
  const float* x  = (const float*)d_in[0];
  const float* Wq = (const float*)d_in[1];
  const float* Wk = (const float*)d_in[2];
  const float* Wv = (const float*)d_in[3];
  const float* Wo = (const float*)d_in[4];
  float* out = (float*)d_out;

  const size_t tsz = (size_t)Bd * Sd * Dd;  // 4 Mi elements
  bf16* Qb = (bf16*)d_ws;
  bf16* Kb = Qb + tsz;
  bf16* Vb = Kb + tsz;
  bf16* Ab = Vb + tsz;  // attention out, bf16 [B,S,D]

  const int M = Bd * Sd;  // 4096
  dim3 blk(256);
  dim3 gg(Dd / 64, M / 128);   // (16, 32) = 512 blocks
  dim3 ga(Sd / 64, Bd * Hd);   // (32, 32)

  gemm_mfma<false, true><<<gg, blk, 0, stream>>>(x, Wq, Qb, M, Dd, Dd);
  gemm_mfma<false, true><<<gg, blk, 0, stream>>>(x, Wk, Kb, M, Dd, Dd);
  gemm_mfma<false, true><<<gg, blk, 0, stream>>>(x, Wv, Vb, M, Dd, Dd);
  attn_mfma<<<ga, blk, 0, stream>>>(Qb, Kb, Vb, Ab);
  gemm_mfma<true, false><<<gg, blk, 0, stream>>>(Ab, Wo, out, M, Dd, Dd);
}

// Round 3
// 117.931 us; speedup vs baseline: 10.5385x; 2.5347x over previous
//
#include <hip/hip_runtime.h>
#include <cstdint>

typedef __bf16 bf16;
typedef __bf16 bf16x2 __attribute__((ext_vector_type(2)));
typedef __bf16 bf16x4 __attribute__((ext_vector_type(4)));
typedef __bf16 bf16x8 __attribute__((ext_vector_type(8)));
typedef float f32x4 __attribute__((ext_vector_type(4)));

constexpr int S = 2048, D = 1024, H = 16, HD = 64, B = 2;
constexpr size_t TSZ = (size_t)B * H * S * HD;  // 4 Mi elements

__device__ __forceinline__ f32x4 mfma16(bf16x8 a, bf16x8 b, f32x4 c) {
  return __builtin_amdgcn_mfma_f32_16x16x32_bf16(a, b, c, 0, 0, 0);
}

// async global->LDS, 16B per lane. LDS dest = wave-linear (base + lane*16).
__device__ __forceinline__ void gl_lds16(const bf16* g, bf16* s) {
  __builtin_amdgcn_global_load_lds((__attribute__((address_space(1))) void*)g,
                                   (__attribute__((address_space(3))) void*)s,
                                   16, 0, 0);
}

// ---------------------------------------------------------------------------
// prep: x fp32 -> bf16 (same layout)
// ---------------------------------------------------------------------------
__global__ __launch_bounds__(256) void prep_x(const float* __restrict__ x,
                                              bf16* __restrict__ xb) {
  const size_t i = (size_t)blockIdx.x * 256 + threadIdx.x;
  const float4 a = ((const float4*)x)[2 * i];
  const float4 b = ((const float4*)x)[2 * i + 1];
  bf16x8 o = {(bf16)a.x, (bf16)a.y, (bf16)a.z, (bf16)a.w,
              (bf16)b.x, (bf16)b.y, (bf16)b.z, (bf16)b.w};
  *(bf16x8*)&xb[i * 8] = o;
}

// ---------------------------------------------------------------------------
// prep: W [K][N] fp32 -> Wt [z][N][K] bf16 (transposed), 64x64 LDS tiles
// ---------------------------------------------------------------------------
__global__ __launch_bounds__(256) void prep_w(const float* __restrict__ W0,
                                              const float* __restrict__ W1,
                                              const float* __restrict__ W2,
                                              const float* __restrict__ W3,
                                              bf16* __restrict__ Wt) {
  __shared__ __align__(16) bf16 Lt[64][68];
  const int z = blockIdx.z;
  const float* W = z == 0 ? W0 : z == 1 ? W1 : z == 2 ? W2 : W3;
  const int k0 = blockIdx.x * 64, n0 = blockIdx.y * 64;
  const int t = threadIdx.x, tr = t >> 4, tc = (t & 15) * 4;
#pragma unroll
  for (int p = 0; p < 4; ++p) {
    const int r = 16 * p + tr;
    const float4 v = *(const float4*)&W[(size_t)(k0 + r) * D + n0 + tc];
    Lt[tc + 0][r] = (bf16)v.x;
    Lt[tc + 1][r] = (bf16)v.y;
    Lt[tc + 2][r] = (bf16)v.z;
    Lt[tc + 3][r] = (bf16)v.w;
  }
  __syncthreads();
#pragma unroll
  for (int p = 0; p < 4; ++p) {
    const int n = 16 * p + tr;
    const bf16x4 o = *(const bf16x4*)&Lt[n][tc];
    *(bf16x4*)&Wt[((size_t)z * D + n0 + n) * D + k0 + tc] = o;
  }
}

// ---------------------------------------------------------------------------
// bf16 GEMM, m97 structure: 128x128 tile, BK=64, 4 waves (2x2),
// global_load_lds staging with XOR-preswizzled source, swizzled b128 frags.
// A [M][K] bf16 row-major, Bt [N][K] bf16 row-major.
// MODE 0: C bf16 scattered to [3][B,H,S,Dh] (fused QKV). MODE 1: fp32 [M][D].
// ---------------------------------------------------------------------------
template <int MODE>
__global__ __launch_bounds__(256) void gemm_bt(const bf16* __restrict__ A,
                                               const bf16* __restrict__ Bt,
                                               void* __restrict__ Cp) {
  constexpr int K = 1024;
  __shared__ __align__(16) bf16 As[128 * 64];
  __shared__ __align__(16) bf16 Bs[128 * 64];

  const int bid = blockIdx.x, nwg = gridDim.x;       // nwg % 8 == 0
  const int lg = (bid & 7) * (nwg >> 3) + (bid >> 3);  // XCD-chunked
  const int bm = (lg & 31) * 128;
  const int bn = (lg >> 5) * 128;

  const int t = threadIdx.x, l = t & 63, w = t >> 6;
  const int c = l & 15, g = l >> 4, cx = c & 7;
  const int lrow = l >> 3;                  // row within 1KB LDS chunk
  const int srcc = ((l & 7) ^ lrow) << 3;   // pre-swizzled source k-offset
  const int wm = (w >> 1) * 64, wn = (w & 1) * 64;

  f32x4 acc[4][4] = {};

  for (int kt = 0; kt < K / 64; ++kt) {
    const int k0 = kt * 64;
    __syncthreads();  // prior compute done before overwrite
#pragma unroll
    for (int i = 0; i < 4; ++i) {
      const int ci = i * 4 + w;         // 1KB chunk id (16 per tile)
      const int row = ci * 8 + lrow;    // tile row 0..127
      gl_lds16(A + (size_t)(bm + row) * K + k0 + srcc, As + ci * 512 + l * 8);
      gl_lds16(Bt + (size_t)(bn + row) * K + k0 + srcc, Bs + ci * 512 + l * 8);
    }
    __syncthreads();  // drains vmcnt

    bf16x8 af[4][2], bfv[4][2];
#pragma unroll
    for (int mi = 0; mi < 4; ++mi) {
      const int row = wm + mi * 16 + c;  // row&7 == cx
#pragma unroll
      for (int kh = 0; kh < 2; ++kh)
        af[mi][kh] = *(const bf16x8*)&As[row * 64 + (((kh * 4 + g) ^ cx) << 3)];
    }
#pragma unroll
    for (int ni = 0; ni < 4; ++ni) {
      const int row = wn + ni * 16 + c;
#pragma unroll
      for (int kh = 0; kh < 2; ++kh)
        bfv[ni][kh] = *(const bf16x8*)&Bs[row * 64 + (((kh * 4 + g) ^ cx) << 3)];
    }
#pragma unroll
    for (int mi = 0; mi < 4; ++mi)
#pragma unroll
      for (int ni = 0; ni < 4; ++ni) {
        acc[mi][ni] = mfma16(af[mi][0], bfv[ni][0], acc[mi][ni]);
        acc[mi][ni] = mfma16(af[mi][1], bfv[ni][1], acc[mi][ni]);
      }
  }

  // epilogue: C frag row = 4g+r, col = c (verified mapping)
#pragma unroll
  for (int mi = 0; mi < 4; ++mi)
#pragma unroll
    for (int ni = 0; ni < 4; ++ni)
#pragma unroll
      for (int r = 0; r < 4; ++r) {
        const int m = bm + wm + mi * 16 + 4 * g + r;
        const int n = bn + wn + ni * 16 + c;
        const float v = acc[mi][ni][r];
        if constexpr (MODE == 0) {
          const int which = n >> 10, nn = n & 1023;
          const int h = nn >> 6, d = nn & 63;
          const int bb = m >> 11, s = m & 2047;
          ((bf16*)Cp)[which * TSZ + ((((size_t)bb * H + h) * S + s) << 6) + d] =
              (bf16)v;
        } else {
          ((float*)Cp)[(size_t)m * D + n] = v;
        }
      }
}

// ---------------------------------------------------------------------------
// Flash attention, swapped-QK in-register softmax.
// 4 waves x 16 q-rows = 64-row q-tile; K-tile 64; block does q-tiles
// (qp, 31-qp) for uniform causal work (33 K-tiles per block).
// S^T = mfma(K,Q): lane (g,c) holds S[q=c][kv=16ct+4g+r] -> in-lane softmax.
// O^T = mfma(V^T, P^T): lane holds O[q=c][vd=16ct+4g+r] -> in-lane rescale.
// All LDS tiles 128B rows with chunk'=chunk^(row&7) XOR swizzle.
// ---------------------------------------------------------------------------
__global__ __launch_bounds__(256) void attn3(const bf16* __restrict__ Q,
                                             const bf16* __restrict__ Kg,
                                             const bf16* __restrict__ Vg,
                                             bf16* __restrict__ O) {
  __shared__ __align__(16) bf16 Ks[64 * 64];
  __shared__ __align__(16) bf16 Vt[64 * 64];      // [vd][kv]
  __shared__ __align__(16) bf16 Pb[4][16 * 64];   // per-wave P [q][kv]

  const int bid = blockIdx.x, nwg = gridDim.x;    // 512
  const int lgid = (bid & 7) * (nwg >> 3) + (bid >> 3);
  const int qp = lgid & 15, bh = lgid >> 4;
  const int t = threadIdx.x, l = t & 63, w = t >> 6;
  const int c = l & 15, g = l >> 4, cx = c & 7;
  const int bb = bh >> 4, h = bh & 15;
  const float SC = 0.18033688011112042f;  // (1/8)*log2(e)

  const bf16* Kbase = Kg + (size_t)bh * S * HD;
  const bf16* Vbase = Vg + (size_t)bh * S * HD;

  for (int pass = 0; pass < 2; ++pass) {
    const int qt = pass ? (31 - qp) : qp;
    const int q0 = qt * 64;
    const int qglob = q0 + 16 * w + c;
    const bf16* Qrow = Q + ((size_t)bh * S + qglob) * HD;
    const bf16x8 qf0 = *(const bf16x8*)&Qrow[g * 8];
    const bf16x8 qf1 = *(const bf16x8*)&Qrow[32 + g * 8];

    f32x4 oacc[4] = {};
    float mrun = -1e30f, lrun = 0.f;

    for (int kt = 0; kt <= qt; ++kt) {
      __syncthreads();  // previous tile's reads complete
      // ---- stage K (swizzled row-major) ----
      const bf16* Kt = Kbase + (size_t)kt * 64 * HD;
#pragma unroll
      for (int p = 0; p < 2; ++p) {
        const int idx = t + 256 * p;
        const int kv = idx >> 3, dg = idx & 7;
        *(bf16x8*)&Ks[kv * 64 + ((dg ^ (kv & 7)) << 3)] =
            *(const bf16x8*)&Kt[kv * 64 + dg * 8];
      }
      // ---- stage V transposed (bf16x2 kv-pair writes, conflict-free) ----
      {
        const bf16* Vs = Vbase + (size_t)kt * 64 * HD;
        const int p2 = t & 31, dg = t >> 5;
        const bf16x8 v0 = *(const bf16x8*)&Vs[(2 * p2) * 64 + dg * 8];
        const bf16x8 v1 = *(const bf16x8*)&Vs[(2 * p2 + 1) * 64 + dg * 8];
#pragma unroll
        for (int i = 0; i < 8; ++i) {
          const int vd = 8 * dg + i;  // vd&7 == i
          bf16x2 pr2 = {v0[i], v1[i]};
          *(bf16x2*)&Vt[vd * 64 + (((p2 >> 2) ^ i) << 3) + ((p2 & 3) << 1)] = pr2;
        }
      }
      __syncthreads();

      // ---- S^T = K Q^T ----
      f32x4 st[4];
#pragma unroll
      for (int ct = 0; ct < 4; ++ct) {
        const int krow = ct * 16 + c;  // krow&7 == cx
        const bf16x8 kf0 = *(const bf16x8*)&Ks[krow * 64 + ((g ^ cx) << 3)];
        const bf16x8 kf1 = *(const bf16x8*)&Ks[krow * 64 + (((4 + g) ^ cx) << 3)];
        f32x4 z = {};
        z = mfma16(kf0, qf0, z);
        st[ct] = mfma16(kf1, qf1, z);
      }

      if (kt == qt) {  // causal mask, diagonal tile only
#pragma unroll
        for (int ct = 0; ct < 4; ++ct)
#pragma unroll
          for (int r = 0; r < 4; ++r)
            if (kt * 64 + ct * 16 + 4 * g + r > qglob) st[ct][r] = -1e30f;
      }

      // ---- in-lane online softmax (lane owns q-row c) ----
      float mt = st[0][0];
#pragma unroll
      for (int ct = 0; ct < 4; ++ct)
#pragma unroll
        for (int r = 0; r < 4; ++r) mt = fmaxf(mt, st[ct][r]);
      mt = fmaxf(mt, __shfl_xor(mt, 16));
      mt = fmaxf(mt, __shfl_xor(mt, 32));
      const float mnew = fmaxf(mrun, mt);
      const float fac = __builtin_amdgcn_exp2f((mrun - mnew) * SC);
      mrun = mnew;
      float p[4][4];
      float ps = 0.f;
#pragma unroll
      for (int ct = 0; ct < 4; ++ct)
#pragma unroll
        for (int r = 0; r < 4; ++r) {
          p[ct][r] = __builtin_amdgcn_exp2f((st[ct][r] - mnew) * SC);
          ps += p[ct][r];
        }
      ps += __shfl_xor(ps, 16);
      ps += __shfl_xor(ps, 32);
      lrun = lrun * fac + ps;
#pragma unroll
      for (int ct = 0; ct < 4; ++ct)
#pragma unroll
        for (int r = 0; r < 4; ++r) oacc[ct][r] *= fac;

      // ---- P -> per-wave swizzled LDS (bf16x2), then A-frag reads ----
      bf16* Pw = &Pb[w][0];
#pragma unroll
      for (int ct = 0; ct < 4; ++ct)
#pragma unroll
        for (int pr = 0; pr < 2; ++pr) {
          const int ch = (2 * ct + (g >> 1)) ^ cx;
          bf16x2 pk = {(bf16)p[ct][2 * pr], (bf16)p[ct][2 * pr + 1]};
          *(bf16x2*)&Pw[c * 64 + ch * 8 + (g & 1) * 4 + pr * 2] = pk;
        }
      const bf16x8 pa0 = *(const bf16x8*)&Pw[c * 64 + ((g ^ cx) << 3)];
      const bf16x8 pa1 = *(const bf16x8*)&Pw[c * 64 + (((4 + g) ^ cx) << 3)];

      // ---- O^T += V^T P^T ----
#pragma unroll
      for (int ct = 0; ct < 4; ++ct) {
        const int vrow = ct * 16 + c;
        const bf16x8 vt0 = *(const bf16x8*)&Vt[vrow * 64 + ((g ^ cx) << 3)];
        const bf16x8 vt1 = *(const bf16x8*)&Vt[vrow * 64 + (((4 + g) ^ cx) << 3)];
        oacc[ct] = mfma16(vt0, pa0, oacc[ct]);
        oacc[ct] = mfma16(vt1, pa1, oacc[ct]);
      }
    }

    // ---- epilogue: in-lane normalize, packed u32 stores to [B,S,D] ----
    const float inv = 1.f / lrun;
    bf16* Orow = O + ((size_t)bb * S + qglob) * D + h * 64;
#pragma unroll
    for (int ct = 0; ct < 4; ++ct)
#pragma unroll
      for (int pr = 0; pr < 2; ++pr) {
        bf16x2 pk = {(bf16)(oacc[ct][2 * pr] * inv),
                     (bf16)(oacc[ct][2 * pr + 1] * inv)};
        *(bf16x2*)&Orow[ct * 16 + 4 * g + 2 * pr] = pk;
      }
  }
}

// ---------------------------------------------------------------------------
extern "C" void kernel_launch(void* const* d_in, const int* in_sizes, int n_in,
                              void* d_out, int out_size, void* d_ws, size_t ws_size,
                              hipStream_t stream) {
  const float* x  = (const float*)d_in[0];
  const float* Wq = (const float*)d_in[1];
  const float* Wk = (const float*)d_in[2];
  const float* Wv = (const float*)d_in[3];
  const float* Wo = (const float*)d_in[4];
  float* out = (float*)d_out;

  bf16* xb  = (bf16*)d_ws;                       // 4Mi  (8 MB)
  bf16* Wt  = xb + (size_t)B * S * D;            // 4Mi  (8 MB) [4][1024][1024]
  bf16* QKV = Wt + (size_t)4 * D * D;            // 12Mi (24 MB) [3][B,H,S,Dh]
  bf16* Ab  = QKV + 3 * TSZ;                     // 4Mi  (8 MB) [B*S][D]

  prep_x<<<2048, 256, 0, stream>>>(x, xb);
  prep_w<<<dim3(16, 16, 4), 256, 0, stream>>>(Wq, Wk, Wv, Wo, Wt);
  gemm_bt<0><<<768, 256, 0, stream>>>(xb, Wt, QKV);                  // fused QKV
  attn3<<<512, 256, 0, stream>>>(QKV, QKV + TSZ, QKV + 2 * TSZ, Ab);
  gemm_bt<1><<<256, 256, 0, stream>>>(Ab, Wt + (size_t)3 * D * D, out);
}

// Round 4
// 109.190 us; speedup vs baseline: 11.3823x; 1.0801x over previous
//
#include <hip/hip_runtime.h>
#include <cstdint>

typedef __bf16 bf16;
typedef __bf16 bf16x2 __attribute__((ext_vector_type(2)));
typedef __bf16 bf16x4 __attribute__((ext_vector_type(4)));
typedef __bf16 bf16x8 __attribute__((ext_vector_type(8)));
typedef float f32x4 __attribute__((ext_vector_type(4)));

constexpr int S = 2048, D = 1024, H = 16, HD = 64, B = 2;
constexpr size_t TSZ = (size_t)B * H * S * HD;  // 4 Mi elements

__device__ __forceinline__ f32x4 mfma16(bf16x8 a, bf16x8 b, f32x4 c) {
  return __builtin_amdgcn_mfma_f32_16x16x32_bf16(a, b, c, 0, 0, 0);
}

// async global->LDS, 16B per lane. LDS dest = wave-linear (base + lane*16).
__device__ __forceinline__ void gl_lds16(const bf16* g, bf16* s) {
  __builtin_amdgcn_global_load_lds((__attribute__((address_space(1))) void*)g,
                                   (__attribute__((address_space(3))) void*)s,
                                   16, 0, 0);
}

// ---------------------------------------------------------------------------
// prep: x fp32 -> bf16 (same layout)
// ---------------------------------------------------------------------------
__global__ __launch_bounds__(256) void prep_x(const float* __restrict__ x,
                                              bf16* __restrict__ xb) {
  const size_t i = (size_t)blockIdx.x * 256 + threadIdx.x;
  const float4 a = ((const float4*)x)[2 * i];
  const float4 b = ((const float4*)x)[2 * i + 1];
  bf16x8 o = {(bf16)a.x, (bf16)a.y, (bf16)a.z, (bf16)a.w,
              (bf16)b.x, (bf16)b.y, (bf16)b.z, (bf16)b.w};
  *(bf16x8*)&xb[i * 8] = o;
}

// ---------------------------------------------------------------------------
// prep: W [K][N] fp32 -> Wt [z][N][K] bf16 (transposed), 64x64 LDS tiles
// ---------------------------------------------------------------------------
__global__ __launch_bounds__(256) void prep_w(const float* __restrict__ W0,
                                              const float* __restrict__ W1,
                                              const float* __restrict__ W2,
                                              const float* __restrict__ W3,
                                              bf16* __restrict__ Wt) {
  __shared__ __align__(16) bf16 Lt[64][68];
  const int z = blockIdx.z;
  const float* W = z == 0 ? W0 : z == 1 ? W1 : z == 2 ? W2 : W3;
  const int k0 = blockIdx.x * 64, n0 = blockIdx.y * 64;
  const int t = threadIdx.x, tr = t >> 4, tc = (t & 15) * 4;
#pragma unroll
  for (int p = 0; p < 4; ++p) {
    const int r = 16 * p + tr;
    const float4 v = *(const float4*)&W[(size_t)(k0 + r) * D + n0 + tc];
    Lt[tc + 0][r] = (bf16)v.x;
    Lt[tc + 1][r] = (bf16)v.y;
    Lt[tc + 2][r] = (bf16)v.z;
    Lt[tc + 3][r] = (bf16)v.w;
  }
  __syncthreads();
#pragma unroll
  for (int p = 0; p < 4; ++p) {
    const int n = 16 * p + tr;
    const bf16x4 o = *(const bf16x4*)&Lt[n][tc];
    *(bf16x4*)&Wt[((size_t)z * D + n0 + n) * D + k0 + tc] = o;
  }
}

// ---------------------------------------------------------------------------
// bf16 GEMM, m97 structure: 128x128 tile, BK=64, 4 waves (2x2),
// global_load_lds staging with XOR-preswizzled source, swizzled b128 frags.
// A [M][K] bf16 row-major, Bt [N][K] bf16 row-major.
// MODE 0: C bf16 scattered to [3][B,H,S,Dh] (fused QKV). MODE 1: fp32 [M][D].
// ---------------------------------------------------------------------------
template <int MODE>
__global__ __launch_bounds__(256) void gemm_bt(const bf16* __restrict__ A,
                                               const bf16* __restrict__ Bt,
                                               void* __restrict__ Cp) {
  constexpr int K = 1024;
  __shared__ __align__(16) bf16 As[128 * 64];
  __shared__ __align__(16) bf16 Bs[128 * 64];

  const int bid = blockIdx.x, nwg = gridDim.x;       // nwg % 8 == 0
  const int lg = (bid & 7) * (nwg >> 3) + (bid >> 3);  // XCD-chunked
  const int bm = (lg & 31) * 128;
  const int bn = (lg >> 5) * 128;

  const int t = threadIdx.x, l = t & 63, w = t >> 6;
  const int c = l & 15, g = l >> 4, cx = c & 7;
  const int lrow = l >> 3;                  // row within 1KB LDS chunk
  const int srcc = ((l & 7) ^ lrow) << 3;   // pre-swizzled source k-offset
  const int wm = (w >> 1) * 64, wn = (w & 1) * 64;

  f32x4 acc[4][4] = {};

  for (int kt = 0; kt < K / 64; ++kt) {
    const int k0 = kt * 64;
    __syncthreads();  // prior compute done before overwrite
#pragma unroll
    for (int i = 0; i < 4; ++i) {
      const int ci = i * 4 + w;         // 1KB chunk id (16 per tile)
      const int row = ci * 8 + lrow;    // tile row 0..127
      gl_lds16(A + (size_t)(bm + row) * K + k0 + srcc, As + ci * 512 + l * 8);
      gl_lds16(Bt + (size_t)(bn + row) * K + k0 + srcc, Bs + ci * 512 + l * 8);
    }
    __syncthreads();  // drains vmcnt

    bf16x8 af[4][2], bfv[4][2];
#pragma unroll
    for (int mi = 0; mi < 4; ++mi) {
      const int row = wm + mi * 16 + c;  // row&7 == cx
#pragma unroll
      for (int kh = 0; kh < 2; ++kh)
        af[mi][kh] = *(const bf16x8*)&As[row * 64 + (((kh * 4 + g) ^ cx) << 3)];
    }
#pragma unroll
    for (int ni = 0; ni < 4; ++ni) {
      const int row = wn + ni * 16 + c;
#pragma unroll
      for (int kh = 0; kh < 2; ++kh)
        bfv[ni][kh] = *(const bf16x8*)&Bs[row * 64 + (((kh * 4 + g) ^ cx) << 3)];
    }
#pragma unroll
    for (int mi = 0; mi < 4; ++mi)
#pragma unroll
      for (int ni = 0; ni < 4; ++ni) {
        acc[mi][ni] = mfma16(af[mi][0], bfv[ni][0], acc[mi][ni]);
        acc[mi][ni] = mfma16(af[mi][1], bfv[ni][1], acc[mi][ni]);
      }
  }

  // epilogue: C frag row = 4g+r, col = c (verified mapping)
#pragma unroll
  for (int mi = 0; mi < 4; ++mi)
#pragma unroll
    for (int ni = 0; ni < 4; ++ni)
#pragma unroll
      for (int r = 0; r < 4; ++r) {
        const int m = bm + wm + mi * 16 + 4 * g + r;
        const int n = bn + wn + ni * 16 + c;
        const float v = acc[mi][ni][r];
        if constexpr (MODE == 0) {
          const int which = n >> 10, nn = n & 1023;
          const int h = nn >> 6, d = nn & 63;
          const int bb = m >> 11, s = m & 2047;
          ((bf16*)Cp)[which * TSZ + ((((size_t)bb * H + h) * S + s) << 6) + d] =
              (bf16)v;
        } else {
          ((float*)Cp)[(size_t)m * D + n] = v;
        }
      }
}

// ---------------------------------------------------------------------------
// Flash attention v4: swapped-QK in-register softmax + LPT grid + async-stage
// + defer-max + setprio.
// Grid: 1024 blocks, one (qt,bh) each, qt DESCENDING with bid (LPT: longest
// blocks dispatch first). Same-bh blocks are 32 apart -> same XCD L2.
// 4 waves x 16 q-rows; K-tile 64; K/V prefetched to regs one tile ahead.
// S^T = mfma(K,Q): lane (g,c) holds S[kv=16ct+4g+r][q=c] -> in-lane softmax.
// O^T = mfma(V^T,P^T): lane holds O^T[vd=16ct+4g+r][q=c] -> in-lane rescale.
// ---------------------------------------------------------------------------
__global__ __launch_bounds__(256, 4) void attn3(const bf16* __restrict__ Q,
                                                const bf16* __restrict__ Kg,
                                                const bf16* __restrict__ Vg,
                                                bf16* __restrict__ O) {
  __shared__ __align__(16) bf16 Ks[64 * 64];
  __shared__ __align__(16) bf16 Vt[64 * 64];      // [vd][kv]
  __shared__ __align__(16) bf16 Pb[4][16 * 64];   // per-wave P [q][kv]

  const int bid = blockIdx.x;
  const int qt = 31 - (bid >> 5);       // LPT: big tiles first
  const int bh = bid & 31;              // bh&7 fixed per XCD round-robin
  const int t = threadIdx.x, l = t & 63, w = t >> 6;
  const int c = l & 15, g = l >> 4, cx = c & 7;
  const int bb = bh >> 4, h = bh & 15;
  const float SC = 0.18033688011112042f;   // (1/8)*log2(e)
  const float THRS = 44.3614195558365f;    // 8 / SC (defer-max threshold)

  const bf16* Kbase = Kg + (size_t)bh * S * HD;
  const bf16* Vbase = Vg + (size_t)bh * S * HD;

  const int q0 = qt * 64;
  const int qglob = q0 + 16 * w + c;
  const bf16* Qrow = Q + ((size_t)bh * S + qglob) * HD;
  const bf16x8 qf0 = *(const bf16x8*)&Qrow[g * 8];
  const bf16x8 qf1 = *(const bf16x8*)&Qrow[32 + g * 8];

  // staging index precompute
  const int kv0 = t >> 3, dg0 = t & 7;          // K chunk 0 (rows 0..31)
  const int kv1 = kv0 + 32;                     // K chunk 1 (rows 32..63)
  const int p2 = t & 31, dgv = t >> 5;          // V transpose mapping

  // ---- prologue: load tile 0 into registers ----
  bf16x8 ka0 = *(const bf16x8*)&Kbase[kv0 * 64 + dg0 * 8];
  bf16x8 ka1 = *(const bf16x8*)&Kbase[kv1 * 64 + dg0 * 8];
  bf16x8 va0 = *(const bf16x8*)&Vbase[(2 * p2) * 64 + dgv * 8];
  bf16x8 va1 = *(const bf16x8*)&Vbase[(2 * p2 + 1) * 64 + dgv * 8];

  f32x4 oacc[4] = {};
  float mrun = -1e30f, lrun = 0.f;

  for (int kt = 0; kt <= qt; ++kt) {
    __syncthreads();  // previous tile's LDS reads complete
    // ---- write current regs -> LDS (K swizzled, V transposed) ----
    *(bf16x8*)&Ks[kv0 * 64 + ((dg0 ^ (kv0 & 7)) << 3)] = ka0;
    *(bf16x8*)&Ks[kv1 * 64 + ((dg0 ^ (kv1 & 7)) << 3)] = ka1;
#pragma unroll
    for (int i = 0; i < 8; ++i) {
      const int vd = 8 * dgv + i;  // vd&7 == i
      bf16x2 pr2 = {va0[i], va1[i]};
      *(bf16x2*)&Vt[vd * 64 + (((p2 >> 2) ^ i) << 3) + ((p2 & 3) << 1)] = pr2;
    }
    // ---- issue next tile's loads (overlap with this tile's compute) ----
    bf16x8 kn0 = ka0, kn1 = ka1, vn0 = va0, vn1 = va1;
    if (kt < qt) {
      const bf16* Kt = Kbase + (size_t)(kt + 1) * 64 * HD;
      const bf16* Vs = Vbase + (size_t)(kt + 1) * 64 * HD;
      kn0 = *(const bf16x8*)&Kt[kv0 * 64 + dg0 * 8];
      kn1 = *(const bf16x8*)&Kt[kv1 * 64 + dg0 * 8];
      vn0 = *(const bf16x8*)&Vs[(2 * p2) * 64 + dgv * 8];
      vn1 = *(const bf16x8*)&Vs[(2 * p2 + 1) * 64 + dgv * 8];
    }
    __syncthreads();

    // ---- S^T = K Q^T ----
    f32x4 st[4];
    __builtin_amdgcn_s_setprio(1);
#pragma unroll
    for (int ct = 0; ct < 4; ++ct) {
      const int krow = ct * 16 + c;  // krow&7 == cx
      const bf16x8 kf0 = *(const bf16x8*)&Ks[krow * 64 + ((g ^ cx) << 3)];
      const bf16x8 kf1 = *(const bf16x8*)&Ks[krow * 64 + (((4 + g) ^ cx) << 3)];
      f32x4 z = {};
      z = mfma16(kf0, qf0, z);
      st[ct] = mfma16(kf1, qf1, z);
    }
    __builtin_amdgcn_s_setprio(0);

    if (kt == qt) {  // causal mask, diagonal tile only
#pragma unroll
      for (int ct = 0; ct < 4; ++ct)
#pragma unroll
        for (int r = 0; r < 4; ++r)
          if (kt * 64 + ct * 16 + 4 * g + r > qglob) st[ct][r] = -1e30f;
    }

    // ---- in-lane online softmax (4 lanes per q-row) + defer-max ----
    float mt = st[0][0];
#pragma unroll
    for (int ct = 0; ct < 4; ++ct)
#pragma unroll
      for (int r = 0; r < 4; ++r) mt = fmaxf(mt, st[ct][r]);
    mt = fmaxf(mt, __shfl_xor(mt, 16));
    mt = fmaxf(mt, __shfl_xor(mt, 32));
    if (!__all(mt <= mrun + THRS)) {   // rescale only when max grew a lot
      const float mnew = fmaxf(mrun, mt);
      const float fac = __builtin_amdgcn_exp2f((mrun - mnew) * SC);
      lrun *= fac;
#pragma unroll
      for (int ct = 0; ct < 4; ++ct)
#pragma unroll
        for (int r = 0; r < 4; ++r) oacc[ct][r] *= fac;
      mrun = mnew;
    }
    float p[4][4];
    float ps = 0.f;
#pragma unroll
    for (int ct = 0; ct < 4; ++ct)
#pragma unroll
      for (int r = 0; r < 4; ++r) {
        p[ct][r] = __builtin_amdgcn_exp2f((st[ct][r] - mrun) * SC);
        ps += p[ct][r];
      }
    ps += __shfl_xor(ps, 16);
    ps += __shfl_xor(ps, 32);
    lrun += ps;

    // ---- P -> per-wave swizzled LDS (bf16x2), then A-frag reads ----
    bf16* Pw = &Pb[w][0];
#pragma unroll
    for (int ct = 0; ct < 4; ++ct)
#pragma unroll
      for (int pr = 0; pr < 2; ++pr) {
        const int ch = (2 * ct + (g >> 1)) ^ cx;
        bf16x2 pk = {(bf16)p[ct][2 * pr], (bf16)p[ct][2 * pr + 1]};
        *(bf16x2*)&Pw[c * 64 + ch * 8 + (g & 1) * 4 + pr * 2] = pk;
      }
    const bf16x8 pa0 = *(const bf16x8*)&Pw[c * 64 + ((g ^ cx) << 3)];
    const bf16x8 pa1 = *(const bf16x8*)&Pw[c * 64 + (((4 + g) ^ cx) << 3)];

    // ---- O^T += V^T P^T ----
    __builtin_amdgcn_s_setprio(1);
#pragma unroll
    for (int ct = 0; ct < 4; ++ct) {
      const int vrow = ct * 16 + c;
      const bf16x8 vt0 = *(const bf16x8*)&Vt[vrow * 64 + ((g ^ cx) << 3)];
      const bf16x8 vt1 = *(const bf16x8*)&Vt[vrow * 64 + (((4 + g) ^ cx) << 3)];
      oacc[ct] = mfma16(vt0, pa0, oacc[ct]);
      oacc[ct] = mfma16(vt1, pa1, oacc[ct]);
    }
    __builtin_amdgcn_s_setprio(0);

    ka0 = kn0; ka1 = kn1; va0 = vn0; va1 = vn1;
  }

  // ---- epilogue: in-lane normalize, packed u32 stores to [B,S,D] ----
  const float inv = 1.f / lrun;
  bf16* Orow = O + ((size_t)bb * S + qglob) * D + h * 64;
#pragma unroll
  for (int ct = 0; ct < 4; ++ct)
#pragma unroll
    for (int pr = 0; pr < 2; ++pr) {
      bf16x2 pk = {(bf16)(oacc[ct][2 * pr] * inv),
                   (bf16)(oacc[ct][2 * pr + 1] * inv)};
      *(bf16x2*)&Orow[ct * 16 + 4 * g + 2 * pr] = pk;
    }
}

// ---------------------------------------------------------------------------
extern "C" void kernel_launch(void* const* d_in, const int* in_sizes, int n_in,
                              void* d_out, int out_size, void* d_ws, size_t ws_size,
                              hipStream_t stream) {
  const float* x  = (const float*)d_in[0];
  const float* Wq = (const float*)d_in[1];
  const float* Wk = (const float*)d_in[2];
  const float* Wv = (const float*)d_in[3];
  const float* Wo = (const float*)d_in[4];
  float* out = (float*)d_out;

  bf16* xb  = (bf16*)d_ws;                       // 4Mi  (8 MB)
  bf16* Wt  = xb + (size_t)B * S * D;            // 4Mi  (8 MB) [4][1024][1024]
  bf16* QKV = Wt + (size_t)4 * D * D;            // 12Mi (24 MB) [3][B,H,S,Dh]
  bf16* Ab  = QKV + 3 * TSZ;                     // 4Mi  (8 MB) [B*S][D]

  prep_x<<<2048, 256, 0, stream>>>(x, xb);
  prep_w<<<dim3(16, 16, 4), 256, 0, stream>>>(Wq, Wk, Wv, Wo, Wt);
  gemm_bt<0><<<768, 256, 0, stream>>>(xb, Wt, QKV);                  // fused QKV
  attn3<<<1024, 256, 0, stream>>>(QKV, QKV + TSZ, QKV + 2 * TSZ, Ab);
  gemm_bt<1><<<256, 256, 0, stream>>>(Ab, Wt + (size_t)3 * D * D, out);
}